// Round 14
// baseline (216.453 us; speedup 1.0000x reference)
//
#include <hip/hip_runtime.h>
#include <stdint.h>

// Problem constants
#define B_ 4
#define S_ 2048
#define D_ 1024
#define H_ 16
#define DK_ 64
#define M_ (B_*S_)   // 8192 rows

typedef __attribute__((ext_vector_type(8)))  short bhalf8;   // 8 x bf16 (4 VGPRs)
typedef __attribute__((ext_vector_type(4)))  short bhalf4;   // 4 x bf16 (2 VGPRs)
typedef __attribute__((ext_vector_type(4)))  float floatx4;  // 16x16 MFMA acc
typedef __attribute__((ext_vector_type(16))) float floatx16; // 32x32 MFMA acc
typedef unsigned short bfu;
typedef unsigned int u32;

// fp32 -> bf16 (RNE), branchless
__device__ __forceinline__ bfu f2bf(float f) {
  union { float f; u32 u; } v; v.f = f;
  u32 r = v.u + 0x7FFFu + ((v.u >> 16) & 1u);
  return (bfu)(r >> 16);
}

// packed fp32x2 -> bf16x2 via HW cvt (RNE); lo16 = a, hi16 = b
__device__ __forceinline__ u32 cvtpk(float a, float b) {
  u32 r;
  asm("v_cvt_pk_bf16_f32 %0, %1, %2" : "=v"(r) : "v"(a), "v"(b));
  return r;
}

// async global->LDS, 16B per lane; LDS dest = wave-uniform base + lane*16
__device__ __forceinline__ void gll16(const bfu* g, bfu* l) {
  __builtin_amdgcn_global_load_lds((__attribute__((address_space(1))) void*)g,
                                   (__attribute__((address_space(3))) void*)l,
                                   16, 0, 0);
}

// ---------------- fused conversion kernel: x + 4 weights -> contiguous bf16 ws ----------------
__global__ void cvt_all(const float* __restrict__ x,  const float* __restrict__ wq,
                        const float* __restrict__ wk, const float* __restrict__ wv,
                        const float* __restrict__ wo, bfu* __restrict__ dst) {
  const size_t u = ((size_t)blockIdx.x * blockDim.x + threadIdx.x) * 4;
  const size_t XN = (size_t)M_ * D_;
  const float* src;
  if (u < XN) {
    src = x + u;
  } else {
    const size_t v = u - XN;
    const int wsel = (int)(v >> 20);           // D_*D_ = 2^20
    const size_t off = v & ((size_t)(1u << 20) - 1);
    src = ((wsel == 0) ? wq : (wsel == 1) ? wk : (wsel == 2) ? wv : wo) + off;
  }
  float4 vv = *(const float4*)src;
  ushort4 o;
  o.x = f2bf(vv.x); o.y = f2bf(vv.y); o.z = f2bf(vv.z); o.w = f2bf(vv.w);
  *(ushort4*)(dst + u) = o;
}

// ---------------- GEMM core, 2-phase dbuf (r11 proven): C[128x128] = A * B^T ----------------
__device__ __forceinline__ void gemm_core_2ph(const bfu* __restrict__ A,
                                              const bfu* __restrict__ Bw,
                                              bfu* smem,
                                              int m0, int bn0,
                                              floatx4 (&acc)[4][4])
{
  const int tid  = threadIdx.x;
  const int lane = tid & 63;
  const int g    = lane >> 4;
  const int i16  = lane & 15;
  const int w    = tid >> 6;
  const int wm   = w >> 1, wn = w & 1;

  const int lrow = lane >> 3;
  const int scol = ((lane & 7) ^ lrow) << 3;        // pre-swizzled element col
  const bfu* As = A  + (size_t)(m0  + w * 32 + lrow) * D_ + scol;
  const bfu* Bs = Bw + (size_t)(bn0 + w * 32 + lrow) * D_ + scol;
  const int ldst = w * 4 * 512;

  auto STAGE = [&](int t) {
    bfu* base = smem + (t & 1) * 16384;
    const int k0 = t * 64;
#pragma unroll
    for (int j = 0; j < 4; ++j)
      gll16(As + (size_t)j * 8 * D_ + k0, base + ldst + j * 512);
#pragma unroll
    for (int j = 0; j < 4; ++j)
      gll16(Bs + (size_t)j * 8 * D_ + k0, base + 8192 + ldst + j * 512);
  };

  auto COMPUTE = [&](int t) {
    const char* aTc = (const char*)(smem + (t & 1) * 16384);
    const char* bTc = aTc + 16384;
    __builtin_amdgcn_s_setprio(1);
#pragma unroll
    for (int kb = 0; kb < 2; ++kb) {
      bhalf8 af[4], bf[4];
#pragma unroll
      for (int f = 0; f < 4; ++f) {
        int arow = wm * 64 + f * 16 + i16;
        af[f] = *(const bhalf8*)(aTc + arow * 128 + ((kb * 64 + g * 16) ^ ((arow & 7) << 4)));
        int brow = wn * 64 + f * 16 + i16;
        bf[f] = *(const bhalf8*)(bTc + brow * 128 + ((kb * 64 + g * 16) ^ ((brow & 7) << 4)));
      }
#pragma unroll
      for (int fm = 0; fm < 4; ++fm)
#pragma unroll
        for (int fn = 0; fn < 4; ++fn)
          acc[fm][fn] = __builtin_amdgcn_mfma_f32_16x16x32_bf16(af[fm], bf[fn], acc[fm][fn], 0, 0, 0);
    }
    __builtin_amdgcn_s_setprio(0);
  };

  STAGE(0);
  __syncthreads();
  for (int t = 0; t < 16; ++t) {
    if (t + 1 < 16) STAGE(t + 1);
    COMPUTE(t);
    __syncthreads();
  }
}

// ---------------- fused QKV projection GEMM: C[8192 x 3072] ----------------
__global__ __launch_bounds__(256) void qkv_gemm(const bfu* __restrict__ xb,
                                                const bfu* __restrict__ wqkv,
                                                bfu* __restrict__ Qd,
                                                bfu* __restrict__ Kd,
                                                bfu* __restrict__ Vtd)
{
  __shared__ bfu smem[2 * 16384];
  const int bid = blockIdx.x;
  const int wi   = bid >> 3;
  const int xblk = wi >> 3;
  const int y    = ((bid & 7) << 3) | (wi & 7);
  const int m0   = y * 128;
  const int z    = xblk >> 3;
  const int n0   = (xblk & 7) * 128;
  const int bn0  = xblk * 128;

  floatx4 acc[4][4] = {};
  gemm_core_2ph(xb, wqkv, smem, m0, bn0, acc);

  bfu* dst = (z == 0) ? Qd : (z == 1) ? Kd : Vtd;
  const int lane = threadIdx.x & 63;
  const int g = lane >> 4, i16 = lane & 15;
  const int w = threadIdx.x >> 6, wm = w >> 1, wn = w & 1;
#pragma unroll
  for (int fm = 0; fm < 4; ++fm) {
#pragma unroll
    for (int fn = 0; fn < 4; ++fn) {
      int col = n0 + wn * 64 + fn * 16 + i16;
      int h = col >> 6, dk = col & 63;
#pragma unroll
      for (int r = 0; r < 4; ++r) {
        int mrow = m0 + wm * 64 + fm * 16 + g * 4 + r;
        int b = mrow >> 11, s = mrow & (S_ - 1);
        size_t idx = (z == 2)
            ? ((size_t)((b * H_ + h) * DK_ + dk)) * S_ + s    // V^T
            : ((size_t)((b * H_ + h) * S_ + s)) * DK_ + dk;   // Q,K
        dst[idx] = f2bf(acc[fm][fn][r]);
      }
    }
  }
}

// ---------------- output projection GEMM (fp32 out): C[8192 x 1024] ----------------
__global__ __launch_bounds__(256) void out_gemm(const bfu* __restrict__ Ab,
                                                const bfu* __restrict__ wob,
                                                float* __restrict__ out)
{
  __shared__ bfu smem[2 * 16384];
  const int bid = blockIdx.x;
  const int wi   = bid >> 3;
  const int xblk = wi >> 3;
  const int y    = ((bid & 7) << 3) | (wi & 7);
  const int m0   = y * 128;
  const int n0   = xblk * 128;

  floatx4 acc[4][4] = {};
  gemm_core_2ph(Ab, wob, smem, m0, n0, acc);

  const int lane = threadIdx.x & 63;
  const int g = lane >> 4, i16 = lane & 15;
  const int w = threadIdx.x >> 6, wm = w >> 1, wn = w & 1;
#pragma unroll
  for (int fm = 0; fm < 4; ++fm)
#pragma unroll
    for (int fn = 0; fn < 4; ++fn) {
      int col = n0 + wn * 64 + fn * 16 + i16;
#pragma unroll
      for (int r = 0; r < 4; ++r) {
        int mrow = m0 + wm * 64 + fm * 16 + g * 4 + r;
        out[(size_t)mrow * D_ + col] = acc[fm][fn][r];
      }
    }
}

// ---------------- flash attention (causal): 4 waves x 32q, 32x32 MFMA, pair-staged KV ----------------
// grid (B*H, 8): block runs q-blocks {y0, 15-y0}. Wave w owns q rows [128y+32w, +32);
// ntw = 2y + (w>>1) + 1 (spread 1). Per pair (2 kv-tiles) the block stages K(2x64x64) +
// V^T(2x64x64) into a 32KB buffer (dbuf, 64KB total), prefetch-before-compute, 1 barrier/pair.
// QK: S^T = mfma_32x32x16(K,Q) -> lane holds 32 S values of ONE q (col=lane&31);
// row-max = 31 in-lane + 1 shfl_xor(32). P packed via v_cvt_pk_bf16_f32 and redistributed
// with v_permlane32_swap_b32 (one swap fills two B-frag words for both lane halves).
// PV: O^T = mfma_32x32x16(V^T, P^T), V^T read as ds_read_b128. All LDS reads b128.
template<int BUF>
__device__ __forceinline__ void attn_tile32(const char* smem, int t, int ntw, int qr,
                                            const int (&off)[4],
                                            const bhalf8 (&qa)[4], int l31, int hi,
                                            floatx16 (&ot)[2], float& mC2, float& lp)
{
  const float C2 = 0.125f * 1.44269504f;   // dk^-0.5 * log2(e)
  // ---- S^T = K @ Q^T : sa[cb] = kv block cb*32..+31, col q = l31 ----
  floatx16 sa[2] = {};
#pragma unroll
  for (int cb = 0; cb < 2; ++cb)
#pragma unroll
    for (int ks = 0; ks < 4; ++ks) {
      bhalf8 kf = *(const bhalf8*)(smem + BUF + cb * 4096 + off[ks]);
      sa[cb] = __builtin_amdgcn_mfma_f32_32x32x16_bf16(kf, qa[ks], sa[cb], 0, 0, 0);
    }
  // ---- causal mask (wave's last tile only) ----
  if (t == ntw - 1) {
    const int kv0 = t * 64;
    const int q = qr + l31;
#pragma unroll
    for (int cb = 0; cb < 2; ++cb)
#pragma unroll
      for (int r = 0; r < 16; ++r) {
        int kv = kv0 + cb * 32 + (r & 3) + 8 * (r >> 2) + 4 * hi;
        if (kv > q) sa[cb][r] = -3.0e38f;
      }
  }
  // ---- row max: 31 in-lane + 1 shfl across hi-halves ----
  float pm = sa[0][0];
#pragma unroll
  for (int cb = 0; cb < 2; ++cb)
#pragma unroll
    for (int r = 0; r < 16; ++r)
      pm = fmaxf(pm, sa[cb][r]);
  pm = fmaxf(pm, __shfl_xor(pm, 32));
  const float pmC2 = pm * C2;
  if (!__all(pmC2 - mC2 <= 8.0f)) {       // defer-max (THR=8)
    const float nmax = fmaxf(mC2, pmC2);
    const float al = exp2f(mC2 - nmax);
    mC2 = nmax; lp *= al;
#pragma unroll
    for (int d = 0; d < 2; ++d)
#pragma unroll
      for (int r = 0; r < 16; ++r)
        ot[d][r] *= al;
  }
  const float nm = -mC2;
  // ---- P = exp2(S*C2 - m); pack + permlane-swap into P^T B-frags ----
  // lane's p[r] covers kv-in-chunk (r&3)+8*(r>>2)+4*hi. One swap(A,B) yields frag word
  // for BOTH hi halves: .x = w0 (kv {0,1}/{8,9}), .y = w2 (kv {4,5}/{12,13}).
  u32 W[2][8];
  float ps = 0.f;
#pragma unroll
  for (int cb = 0; cb < 2; ++cb) {
    float p[16];
#pragma unroll
    for (int r = 0; r < 16; ++r) {
      p[r] = exp2f(__builtin_fmaf(sa[cb][r], C2, nm));
      ps += p[r];
    }
    u32 A0 = cvtpk(p[0],  p[1]),  A1 = cvtpk(p[2],  p[3]);
    u32 B0 = cvtpk(p[4],  p[5]),  B1 = cvtpk(p[6],  p[7]);
    u32 A2 = cvtpk(p[8],  p[9]),  A3 = cvtpk(p[10], p[11]);
    u32 B2 = cvtpk(p[12], p[13]), B3 = cvtpk(p[14], p[15]);
    asm volatile("v_permlane32_swap_b32 %0, %1" : "+v"(A0), "+v"(B0));
    asm volatile("v_permlane32_swap_b32 %0, %1" : "+v"(A1), "+v"(B1));
    asm volatile("v_permlane32_swap_b32 %0, %1" : "+v"(A2), "+v"(B2));
    asm volatile("v_permlane32_swap_b32 %0, %1" : "+v"(A3), "+v"(B3));
    W[cb][0] = A0; W[cb][1] = A1; W[cb][2] = B0; W[cb][3] = B1;  // kv-chunk 2cb
    W[cb][4] = A2; W[cb][5] = A3; W[cb][6] = B2; W[cb][7] = B3;  // kv-chunk 2cb+1
  }
  lp += ps;
  // ---- O^T += V^T @ P^T ----
#pragma unroll
  for (int c = 0; c < 4; ++c) {
    union { u32 u[4]; bhalf8 h; } pf;
    pf.u[0] = W[c >> 1][(c & 1) * 4 + 0];
    pf.u[1] = W[c >> 1][(c & 1) * 4 + 1];
    pf.u[2] = W[c >> 1][(c & 1) * 4 + 2];
    pf.u[3] = W[c >> 1][(c & 1) * 4 + 3];
#pragma unroll
    for (int dh = 0; dh < 2; ++dh) {
      bhalf8 vf = *(const bhalf8*)(smem + BUF + 8192 + dh * 4096 + off[c]);
      ot[dh] = __builtin_amdgcn_mfma_f32_32x32x16_bf16(vf, pf.h, ot[dh], 0, 0, 0);
    }
  }
}

__global__ __launch_bounds__(256) void attn_kernel(const bfu* __restrict__ Q,
                                                   const bfu* __restrict__ Kc,
                                                   const bfu* __restrict__ Vt,
                                                   bfu* __restrict__ Oc)
{
  __shared__ char smem[2 * 32768];     // dbuf of pair-buffers [K0 8K][V0 8K][K1 8K][V1 8K]
  const int tid = threadIdx.x;
  const int lane = tid & 63;
  const int w = tid >> 6;              // 0..3
  const int l31 = lane & 31, hi = lane >> 5;
  const int bh = blockIdx.x;
  const int y0 = blockIdx.y;           // 0..7

  const bfu* Qb = Q  + (size_t)bh * S_ * DK_;
  const bfu* Kb = Kc + (size_t)bh * S_ * DK_;
  const bfu* Vb = Vt + (size_t)bh * DK_ * S_;
  const int b = bh >> 4, h = bh & 15;

  // per-lane LDS read offsets: row = (cb|dh)*32 + l31 (handled by +4096 steps),
  // byte col = ((x*2+hi) ^ (lane&7)) << 4, x = ks (K) or c (V)
  int off[4];
#pragma unroll
  for (int x = 0; x < 4; ++x)
    off[x] = l31 * 128 + ((((x << 1) | hi) ^ (lane & 7)) << 4);

  // staging: thread covers 2x16B of K and 2x16B of V per tile
  const int srow = tid >> 2;           // 0..63
  const int scq  = tid & 3;            // 0..3
  const bfu* kgp = Kb + srow * DK_ + scq * 16;          // +4096 elems per tile
  const bfu* vgp = Vb + (size_t)srow * S_ + scq * 16;   // +64 elems per tile
  const int swz = (srow & 7) << 4;
  char* kld0 = smem + srow * 128 + ((scq * 32)      ^ swz);
  char* kld1 = smem + srow * 128 + ((scq * 32 + 16) ^ swz);
  char* vld0 = smem + 8192 + srow * 128 + ((scq * 32)      ^ swz);
  char* vld1 = smem + 8192 + srow * 128 + ((scq * 32 + 16) ^ swz);

  for (int pass = 0; pass < 2; ++pass) {
    const int y = pass ? (15 - y0) : y0;
    const int ntw = 2 * y + (w >> 1) + 1;
    const int qr = y * 128 + w * 32;
    const int npair = y + 1;

    // Q B-frags: col q = qr+l31, k slice ks: elems ks*16 + 8*hi .. +7
    bhalf8 qa[4];
#pragma unroll
    for (int ks = 0; ks < 4; ++ks)
      qa[ks] = *(const bhalf8*)(Qb + (size_t)(qr + l31) * DK_ + ks * 16 + 8 * hi);

    floatx16 ot[2] = {};                 // O^T: col q=l31, rows dk = dh*32 + crow(r,hi)
    float mC2 = -1.0e30f;
    float lp  = 0.f;

    bhalf8 ka0, ka1, va0, va1, kb0, kb1, vb0, vb1;
    // prologue: pair 0 (tiles 0,1) -> buf0
    ka0 = *(const bhalf8*)kgp;            ka1 = *(const bhalf8*)(kgp + 8);
    va0 = *(const bhalf8*)vgp;            va1 = *(const bhalf8*)(vgp + 8);
    kb0 = *(const bhalf8*)(kgp + 4096);   kb1 = *(const bhalf8*)(kgp + 4104);
    vb0 = *(const bhalf8*)(vgp + 64);     vb1 = *(const bhalf8*)(vgp + 72);
    *(bhalf8*)kld0 = ka0; *(bhalf8*)kld1 = ka1;
    *(bhalf8*)vld0 = va0; *(bhalf8*)vld1 = va1;
    *(bhalf8*)(kld0 + 16384) = kb0; *(bhalf8*)(kld1 + 16384) = kb1;
    *(bhalf8*)(vld0 + 16384) = vb0; *(bhalf8*)(vld1 + 16384) = vb1;
    __syncthreads();

    for (int i = 0; ; ++i) {
      // ---- half A: compute pair 2i from buf0; prefetch pair 2i+1 ----
      const int pa = 2 * i + 1;
      const bool morea = (pa < npair);
      if (morea) {
        const size_t ko = (size_t)(2 * pa) * 4096;
        const int vo = 2 * pa * 64;
        ka0 = *(const bhalf8*)(kgp + ko);        ka1 = *(const bhalf8*)(kgp + ko + 8);
        va0 = *(const bhalf8*)(vgp + vo);        va1 = *(const bhalf8*)(vgp + vo + 8);
        kb0 = *(const bhalf8*)(kgp + ko + 4096); kb1 = *(const bhalf8*)(kgp + ko + 4104);
        vb0 = *(const bhalf8*)(vgp + vo + 64);   vb1 = *(const bhalf8*)(vgp + vo + 72);
      }
      {
        const int t0 = 4 * i;
        attn_tile32<0>(smem, t0, ntw, qr, off, qa, l31, hi, ot, mC2, lp);
        if (t0 + 1 < ntw)
          attn_tile32<16384>(smem, t0 + 1, ntw, qr, off, qa, l31, hi, ot, mC2, lp);
      }
      if (!morea) break;
      *(bhalf8*)(kld0 + 32768) = ka0; *(bhalf8*)(kld1 + 32768) = ka1;
      *(bhalf8*)(vld0 + 32768) = va0; *(bhalf8*)(vld1 + 32768) = va1;
      *(bhalf8*)(kld0 + 49152) = kb0; *(bhalf8*)(kld1 + 49152) = kb1;
      *(bhalf8*)(vld0 + 49152) = vb0; *(bhalf8*)(vld1 + 49152) = vb1;
      __syncthreads();

      // ---- half B: compute pair 2i+1 from buf1; prefetch pair 2i+2 ----
      const int pb = 2 * i + 2;
      const bool moreb = (pb < npair);
      if (moreb) {
        const size_t ko = (size_t)(2 * pb) * 4096;
        const int vo = 2 * pb * 64;
        ka0 = *(const bhalf8*)(kgp + ko);        ka1 = *(const bhalf8*)(kgp + ko + 8);
        va0 = *(const bhalf8*)(vgp + vo);        va1 = *(const bhalf8*)(vgp + vo + 8);
        kb0 = *(const bhalf8*)(kgp + ko + 4096); kb1 = *(const bhalf8*)(kgp + ko + 4104);
        vb0 = *(const bhalf8*)(vgp + vo + 64);   vb1 = *(const bhalf8*)(vgp + vo + 72);
      }
      {
        const int t0 = 4 * i + 2;
        attn_tile32<32768>(smem, t0, ntw, qr, off, qa, l31, hi, ot, mC2, lp);
        if (t0 + 1 < ntw)
          attn_tile32<49152>(smem, t0 + 1, ntw, qr, off, qa, l31, hi, ot, mC2, lp);
      }
      if (!moreb) break;
      *(bhalf8*)kld0 = ka0; *(bhalf8*)kld1 = ka1;
      *(bhalf8*)vld0 = va0; *(bhalf8*)vld1 = va1;
      *(bhalf8*)(kld0 + 16384) = kb0; *(bhalf8*)(kld1 + 16384) = kb1;
      *(bhalf8*)(vld0 + 16384) = vb0; *(bhalf8*)(vld1 + 16384) = vb1;
      __syncthreads();
    }
    __syncthreads();   // all waves done with buffers before next pass reuses them

    // ---- epilogue: l across hi-halves, divide, store O^T ----
    float lt = lp + __shfl_xor(lp, 32);
    const float rl = 1.0f / lt;
    const size_t rowbase = (size_t)(b * S_ + qr + l31) * D_ + h * 64;
#pragma unroll
    for (int dh = 0; dh < 2; ++dh)
#pragma unroll
      for (int q4 = 0; q4 < 4; ++q4) {
        union { u32 u[2]; uint2 v; } ov;
        ov.u[0] = cvtpk(ot[dh][q4 * 4 + 0] * rl, ot[dh][q4 * 4 + 1] * rl);
        ov.u[1] = cvtpk(ot[dh][q4 * 4 + 2] * rl, ot[dh][q4 * 4 + 3] * rl);
        *(uint2*)(Oc + rowbase + dh * 32 + q4 * 8 + 4 * hi) = ov.v;
      }
  }
}

// ---------------- launch ----------------
extern "C" void kernel_launch(void* const* d_in, const int* in_sizes, int n_in,
                              void* d_out, int out_size, void* d_ws, size_t ws_size,
                              hipStream_t stream)
{
  const float* x  = (const float*)d_in[0];
  const float* wq = (const float*)d_in[1];
  const float* wk = (const float*)d_in[2];
  const float* wv = (const float*)d_in[3];
  const float* wo = (const float*)d_in[4];

  bfu* xb  = (bfu*)d_ws;                          // [8192][1024]
  bfu* wqb = xb  + (size_t)M_ * D_;               // [3072][1024] = W_qkv contiguous
  bfu* wob = wqb + (size_t)3 * D_ * D_;           // [1024][1024]
  bfu* Qd  = wob + (size_t)D_ * D_;               // [bh][s][dk]
  bfu* Kd  = Qd  + (size_t)M_ * D_;               // [bh][s][dk]
  bfu* Vtd = Kd  + (size_t)M_ * D_;               // [bh][dk][s]
  bfu* Ad  = Vtd + (size_t)M_ * D_;               // attn out bf16 [b][s][d]

  const size_t total = (size_t)M_ * D_ + 4 * (size_t)D_ * D_;   // 12582912
  cvt_all<<<(int)(total / 4 / 256), 256, 0, stream>>>(x, wq, wk, wv, wo, xb);

  qkv_gemm<<<1536, 256, 0, stream>>>(xb, wqb, Qd, Kd, Vtd);
  attn_kernel<<<dim3(B_ * H_, 8), 256, 0, stream>>>(Qd, Kd, Vtd, Ad);
  out_gemm<<<512, 256, 0, stream>>>(Ad, wob, (float*)d_out);
}